// Round 10
// baseline (342.699 us; speedup 1.0000x reference)
//
#include <hip/hip_runtime.h>

typedef __attribute__((ext_vector_type(8))) short bf16x8;
typedef __attribute__((ext_vector_type(4))) float floatx4;

#define B_    4
#define N_    2048
#define DIM_  512
#define NH_   8
#define HD_   64
#define SCALE_ 0.125f
#define SL2E_ (0.125f * 1.44269504f)   // scale * log2(e), folded into Q

__device__ __forceinline__ unsigned short f32_to_bf16(float f) {
    unsigned int u = __float_as_uint(f);
    u += 0x7FFFu + ((u >> 16) & 1u);   // round-to-nearest-even
    return (unsigned short)(u >> 16);
}

__device__ __forceinline__ float bf16_to_f32(unsigned short u) {
    return __uint_as_float(((unsigned int)u) << 16);
}

__device__ __forceinline__ floatx4 mfma16(bf16x8 a, bf16x8 b, floatx4 c) {
    return __builtin_amdgcn_mfma_f32_16x16x32_bf16(a, b, c, 0, 0, 0);
}

__device__ __forceinline__ floatx4 fzero4() {
    floatx4 z = {0.f, 0.f, 0.f, 0.f};
    return z;
}

// async global->LDS DMA, 16B per lane. lds dest is wave-uniform base; HW adds lane*16.
__device__ __forceinline__ void async16(const unsigned short* g, unsigned short* l) {
    __builtin_amdgcn_global_load_lds((const __attribute__((address_space(1))) void*)g,
                                     (__attribute__((address_space(3))) void*)l,
                                     16, 0, 0);
}

// ---------------- LayerNorm: x[8192][512] fp32 -> xn bf16 ----------------
__global__ __launch_bounds__(256) void ln_kernel(const float* __restrict__ x,
                                                 const float* __restrict__ w,
                                                 const float* __restrict__ b,
                                                 unsigned short* __restrict__ xn) {
    int row = blockIdx.x;
    int tid = threadIdx.x;
    int lane = tid & 63, wid = tid >> 6;
    const float2 v = ((const float2*)(x + (size_t)row * DIM_))[tid];
    float s = v.x + v.y;
    float sq = v.x * v.x + v.y * v.y;
#pragma unroll
    for (int off = 1; off < 64; off <<= 1) {
        s  += __shfl_xor(s, off, 64);
        sq += __shfl_xor(sq, off, 64);
    }
    __shared__ float red[2][4];
    if (lane == 0) { red[0][wid] = s; red[1][wid] = sq; }
    __syncthreads();
    s  = red[0][0] + red[0][1] + red[0][2] + red[0][3];
    sq = red[1][0] + red[1][1] + red[1][2] + red[1][3];
    float mu   = s * (1.f / DIM_);
    float var  = sq * (1.f / DIM_) - mu * mu;
    float rstd = rsqrtf(var + 1e-5f);
    float2 wv = ((const float2*)w)[tid];
    float2 bv = ((const float2*)b)[tid];
    float y0 = (v.x - mu) * rstd * wv.x + bv.x;
    float y1 = (v.y - mu) * rstd * wv.y + bv.y;
    unsigned int pack = (unsigned int)f32_to_bf16(y0) |
                        ((unsigned int)f32_to_bf16(y1) << 16);
    ((unsigned int*)xn)[(size_t)row * (DIM_ / 2) + tid] = pack;
}

// ---------------- fp32 -> bf16 convert (both weight matrices, one launch) ----------------
__global__ __launch_bounds__(256) void cvt_kernel(const float* __restrict__ srcA, int na,
                                                  const float* __restrict__ srcB, int nb,
                                                  unsigned short* __restrict__ dstA,
                                                  unsigned short* __restrict__ dstB) {
    int idx = blockIdx.x * 256 + threadIdx.x;
    if (idx < na)            dstA[idx] = f32_to_bf16(srcA[idx]);
    else if (idx < na + nb)  dstB[idx - na] = f32_to_bf16(srcB[idx - na]);
}

// ======== m97-style LDS-staged GEMM core, 512-thread / 8-wave variant ========
// 128x128 block tile, BK=32, dbuf LDS; wave tile 32x64 (acc[2][4]).
// 8 light waves per barrier -> drain overlaps with other waves' MFMA.
#define GEMM_CORE512(A_, B_ptr, am0, bn0)                                           \
    __shared__ unsigned short Alds[2][128][32];                                     \
    __shared__ unsigned short Blds[2][128][32];                                     \
    int tid = threadIdx.x, lane = tid & 63, wid = tid >> 6;                         \
    int l15 = lane & 15, quad = lane >> 4;                                          \
    int wmloc = (wid >> 1) * 32, wnloc = (wid & 1) * 64;                            \
    int sr = lane >> 2;                                                             \
    int sc = (lane & 3) * 8;                                                        \
    int srow0 = 16 * wid;                                                           \
    floatx4 acc[2][4];                                                              \
    _Pragma("unroll")                                                               \
    for (int i = 0; i < 2; i++)                                                     \
        _Pragma("unroll")                                                           \
        for (int j = 0; j < 4; j++) acc[i][j] = fzero4();                           \
    int buf = 0;                                                                    \
    async16(A_ + (size_t)(am0 + srow0 + sr) * DIM_ + sc, &Alds[0][srow0][0]);       \
    async16(B_ptr + (size_t)(bn0 + srow0 + sr) * DIM_ + sc, &Blds[0][srow0][0]);    \
    __syncthreads();                                                                \
    for (int t = 0; t < 16; t++) {                                                  \
        if (t < 15) {                                                               \
            int k0 = (t + 1) * 32;                                                  \
            async16(A_ + (size_t)(am0 + srow0 + sr) * DIM_ + k0 + sc,               \
                    &Alds[buf ^ 1][srow0][0]);                                      \
            async16(B_ptr + (size_t)(bn0 + srow0 + sr) * DIM_ + k0 + sc,            \
                    &Blds[buf ^ 1][srow0][0]);                                      \
        }                                                                           \
        bf16x8 av[2], bv[4];                                                        \
        _Pragma("unroll")                                                           \
        for (int i = 0; i < 2; i++)                                                 \
            av[i] = *(const bf16x8*)(&Alds[buf][wmloc + 16 * i + l15][quad * 8]);   \
        _Pragma("unroll")                                                           \
        for (int j = 0; j < 4; j++)                                                 \
            bv[j] = *(const bf16x8*)(&Blds[buf][wnloc + 16 * j + l15][quad * 8]);   \
        _Pragma("unroll")                                                           \
        for (int i = 0; i < 2; i++)                                                 \
            _Pragma("unroll")                                                       \
            for (int j = 0; j < 4; j++)                                             \
                acc[i][j] = mfma16(av[i], bv[j], acc[i][j]);                        \
        __syncthreads();                                                            \
        buf ^= 1;                                                                   \
    }

// ---------------- QKV GEMM: [8192,512] x [1536,512]^T, scatter epilogue ----------------
__global__ __launch_bounds__(512, 6) void qkv_gemm(const unsigned short* __restrict__ A,
                                                   const unsigned short* __restrict__ Bw,
                                                   const float* __restrict__ bias,
                                                   unsigned short* __restrict__ Qh,
                                                   unsigned short* __restrict__ Kh,
                                                   unsigned short* __restrict__ Vt) {
    int am0 = blockIdx.x * 128, bn0 = blockIdx.y * 128;
    GEMM_CORE512(A, Bw, am0, bn0)

    if (bn0 >= 1024) {
        // ---- V path: per-wave LDS transpose -> coalesced Vt[d][t] b128 writes ----
        unsigned short* sc_ = &Alds[0][0][0] + wid * (16 * 40);   // 1280 B/wave
        int m0 = am0 + wmloc;
        int bidx = m0 >> 11;
        int t0 = m0 & 2047;
#pragma unroll
        for (int j = 0; j < 4; j++) {
            float bias_n = bias[bn0 + wnloc + 16 * j + l15];
#pragma unroll
            for (int i = 0; i < 2; i++)
#pragma unroll
                for (int r = 0; r < 4; r++)
                    sc_[l15 * 40 + 16 * i + quad * 4 + r] =
                        f32_to_bf16(acc[i][j][r] + bias_n);
            int nr = lane >> 2;                       // 0..15
            int rem = (bn0 - 1024) + wnloc + 16 * j + nr;
            int head = rem >> 6, d = rem & 63;
            bf16x8 vv = *(const bf16x8*)(sc_ + nr * 40 + (lane & 3) * 8);
            *(bf16x8*)(Vt + ((size_t)(bidx * NH_ + head) * HD_ + d) * N_ +
                       t0 + (lane & 3) * 8) = vv;
        }
    } else {
        // ---- Q/K path (32B-run b16 stores) ----
#pragma unroll
        for (int i = 0; i < 2; i++) {
#pragma unroll
            for (int j = 0; j < 4; j++) {
                int n = bn0 + wnloc + 16 * j + l15;
                float bias_n = bias[n];
                int which = n >> 9;
                int rem = n & 511;
                int head = rem >> 6;
                int d = rem & 63;
#pragma unroll
                for (int r = 0; r < 4; r++) {
                    int m = am0 + wmloc + 16 * i + quad * 4 + r;
                    int b = m >> 11;
                    int t = m & 2047;
                    float val = acc[i][j][r] + bias_n;
                    if (which == 0) {
                        Qh[((size_t)(b * NH_ + head) * N_ + t) * HD_ + d] =
                            f32_to_bf16(val * SL2E_);
                    } else {
                        Kh[((size_t)(b * NH_ + head) * N_ + t) * HD_ + d] =
                            f32_to_bf16(val);
                    }
                }
            }
        }
    }
}

// ---------------- Out projection: [8192,512] x [512,512]^T + bias -> fp32 ----------------
__global__ __launch_bounds__(512, 4) void out_gemm(const unsigned short* __restrict__ A,
                                                   const unsigned short* __restrict__ Bw,
                                                   const float* __restrict__ bias,
                                                   float* __restrict__ out) {
    int am0 = blockIdx.x * 128, bn0 = blockIdx.y * 128;
    GEMM_CORE512(A, Bw, am0, bn0)

#pragma unroll
    for (int i = 0; i < 2; i++) {
#pragma unroll
        for (int j = 0; j < 4; j++) {
            int n = bn0 + wnloc + 16 * j + l15;
            float bias_n = bias[n];
#pragma unroll
            for (int r = 0; r < 4; r++) {
                int m = am0 + wmloc + 16 * i + quad * 4 + r;
                out[(size_t)m * DIM_ + n] = acc[i][j][r] + bias_n;
            }
        }
    }
}

// ---------------- Flash attention, fixed-max softmax, split-KV x4 ----------------
// grid (16 qtiles, 32 bh, 4 splits) = 2048 blocks. LDS 25.6 KB -> 6 blocks/CU
// (Pl shrunk to one 16-row buffer per wave; the two m-halves are processed
// sequentially through it, V-frags re-read per half). Q pre-scaled by
// scale*log2e. Partials combined exactly by combine_kernel.
__global__ __launch_bounds__(256, 6) void attn_kernel(const unsigned short* __restrict__ Qh,
                                                      const unsigned short* __restrict__ Kh,
                                                      const unsigned short* __restrict__ Vtg,
                                                      unsigned short* __restrict__ Opart,
                                                      float* __restrict__ lpart) {
    int bh = blockIdx.y;
    int b = bh >> 3, head = bh & 7;
    int qt = blockIdx.x;
    int split = blockIdx.z;
    int kv0 = split << 9;                  // split * 512
    int tid = threadIdx.x, lane = tid & 63, w = tid >> 6;
    int l15 = lane & 15, quad = lane >> 4;

    const unsigned short* Qp = Qh + (size_t)bh * N_ * HD_;
    const unsigned short* Kg = Kh + (size_t)bh * N_ * HD_;
    const unsigned short* Vg = Vtg + (size_t)bh * HD_ * N_;

    int q0 = qt * 128 + w * 32;

    bf16x8 aQ[2][2];
#pragma unroll
    for (int mh = 0; mh < 2; mh++) {
        const unsigned short* qrow = Qp + (size_t)(q0 + mh * 16 + l15) * HD_ + quad * 8;
        aQ[mh][0] = *(const bf16x8*)(qrow);
        aQ[mh][1] = *(const bf16x8*)(qrow + 32);
    }

    floatx4 of[2][4];
#pragma unroll
    for (int mh = 0; mh < 2; mh++)
#pragma unroll
        for (int t = 0; t < 4; t++) of[mh][t] = fzero4();
    floatx4 lacc[2];
    lacc[0] = fzero4(); lacc[1] = fzero4();

    const short onebf = (short)0x3F80;   // bf16 1.0
    bf16x8 ones = {onebf, onebf, onebf, onebf, onebf, onebf, onebf, onebf};

    __shared__ unsigned short Kt[64][64];      // 8 KB, XOR-swizzled, single-buffered
    __shared__ unsigned short Vs[64][64];      // 8 KB
    __shared__ unsigned short Pl[4][16][72];   // 9 KB, wave-private, reused per m-half

    int srow = lane >> 3;                 // 0..7
    int scol = ((lane & 7) ^ srow) * 8;   // shorts

    int swz0 = (quad ^ (l15 & 7)) * 8;
    int swz1 = ((quad + 4) ^ (l15 & 7)) * 8;

    unsigned short* myP = &Pl[w][0][0];
    for (int kv = kv0; kv < kv0 + 512; kv += 64) {
#pragma unroll
        for (int i = 0; i < 2; i++) {
            int r0 = 16 * w + 8 * i;
            async16(Kg + (size_t)(kv + r0 + srow) * HD_ + scol, &Kt[r0][0]);
            async16(Vg + (size_t)(r0 + srow) * N_ + kv + scol, &Vs[r0][0]);
        }
        __syncthreads();
        // K fragments, shared across both m-halves
        bf16x8 kf[8];
#pragma unroll
        for (int h = 0; h < 4; h++) {
            kf[2 * h]     = *(const bf16x8*)(&Kt[16 * h + l15][swz0]);
            kf[2 * h + 1] = *(const bf16x8*)(&Kt[16 * h + l15][swz1]);
        }
#pragma unroll
        for (int mh = 0; mh < 2; mh++) {
            floatx4 c[4];
#pragma unroll
            for (int h = 0; h < 4; h++) {
                floatx4 cc = fzero4();
                cc = mfma16(aQ[mh][0], kf[2 * h], cc);
                cc = mfma16(aQ[mh][1], kf[2 * h + 1], cc);
                c[h] = cc;
            }
            unsigned short* pw = myP + (quad * 4) * 72 + l15;
#pragma unroll
            for (int h = 0; h < 4; h++)
#pragma unroll
                for (int r = 0; r < 4; r++)
                    pw[r * 72 + h * 16] = f32_to_bf16(exp2f(c[h][r]));
            const unsigned short* pr = myP + l15 * 72;
            bf16x8 aP0 = *(const bf16x8*)(pr + quad * 8);
            bf16x8 aP1 = *(const bf16x8*)(pr + 32 + quad * 8);
#pragma unroll
            for (int t = 0; t < 4; t++) {
                bf16x8 v0 = *(const bf16x8*)(&Vs[16 * t + l15][swz0]);
                bf16x8 v1 = *(const bf16x8*)(&Vs[16 * t + l15][swz1]);
                of[mh][t] = mfma16(aP0, v0, of[mh][t]);
                of[mh][t] = mfma16(aP1, v1, of[mh][t]);
            }
            lacc[mh] = mfma16(aP0, ones, lacc[mh]);
            lacc[mh] = mfma16(aP1, ones, lacc[mh]);
        }
        __syncthreads();
    }

    unsigned short* Od = Opart + (size_t)split * B_ * N_ * DIM_;
#pragma unroll
    for (int mh = 0; mh < 2; mh++) {
        float inv[4];
#pragma unroll
        for (int r = 0; r < 4; r++) inv[r] = 1.f / lacc[mh][r];
#pragma unroll
        for (int t = 0; t < 4; t++) {
#pragma unroll
            for (int r = 0; r < 4; r++) {
                int t_tok = q0 + mh * 16 + quad * 4 + r;
                int d = 16 * t + l15;
                Od[((size_t)b * N_ + t_tok) * DIM_ + head * HD_ + d] =
                    f32_to_bf16(of[mh][t][r] * inv[r]);
            }
        }
        if (l15 == 0) {
#pragma unroll
            for (int r = 0; r < 4; r++) {
                int t_tok = q0 + mh * 16 + quad * 4 + r;
                lpart[((size_t)split * B_ * NH_ + bh) * N_ + t_tok] = lacc[mh][r];
            }
        }
    }
}

// ---------------- combine: Obuf = sum_s l_s*O_s / sum_s l_s, bf16 ----------------
__global__ __launch_bounds__(256) void combine_kernel(const unsigned short* __restrict__ Opart,
                                                      const float* __restrict__ lpart,
                                                      unsigned short* __restrict__ Obuf) {
    int idx = blockIdx.x * 256 + threadIdx.x;   // 4-element groups
    int row = idx >> 7;
    int head = (idx & 127) >> 4;
    int b = row >> 11, t = row & 2047;
    size_t li = (size_t)(b * NH_ + head) * N_ + t;
    const size_t LSTRIDE = (size_t)B_ * NH_ * N_;
    const size_t OSTRIDE = (size_t)B_ * N_ * DIM_;
    float l[4];
#pragma unroll
    for (int s = 0; s < 4; s++) l[s] = lpart[s * LSTRIDE + li];
    float inv = 1.f / (l[0] + l[1] + l[2] + l[3]);
    float acc0 = 0.f, acc1 = 0.f, acc2 = 0.f, acc3 = 0.f;
#pragma unroll
    for (int s = 0; s < 4; s++) {
        float ws = l[s] * inv;
        ushort4 a = ((const ushort4*)(Opart + s * OSTRIDE))[idx];
        acc0 += ws * bf16_to_f32(a.x);
        acc1 += ws * bf16_to_f32(a.y);
        acc2 += ws * bf16_to_f32(a.z);
        acc3 += ws * bf16_to_f32(a.w);
    }
    ushort4 o;
    o.x = f32_to_bf16(acc0);
    o.y = f32_to_bf16(acc1);
    o.z = f32_to_bf16(acc2);
    o.w = f32_to_bf16(acc3);
    ((ushort4*)Obuf)[idx] = o;
}

extern "C" void kernel_launch(void* const* d_in, const int* in_sizes, int n_in,
                              void* d_out, int out_size, void* d_ws, size_t ws_size,
                              hipStream_t stream) {
    const float* x     = (const float*)d_in[0];
    const float* ln_w  = (const float*)d_in[1];
    const float* ln_b  = (const float*)d_in[2];
    const float* qkv_w = (const float*)d_in[3];
    const float* qkv_b = (const float*)d_in[4];
    const float* out_w = (const float*)d_in[5];
    const float* out_b = (const float*)d_in[6];
    float* out = (float*)d_out;

    char* ws = (char*)d_ws;
    const size_t TOK = (size_t)B_ * N_;                 // 8192
    unsigned short* xn    = (unsigned short*)ws;  ws += TOK * DIM_ * 2;                 // 8 MB
    unsigned short* wq_bf = (unsigned short*)ws;  ws += (size_t)3 * DIM_ * DIM_ * 2;    // 1.5 MB
    unsigned short* wo_bf = (unsigned short*)ws;  ws += (size_t)DIM_ * DIM_ * 2;        // 0.5 MB
    unsigned short* Qh    = (unsigned short*)ws;  ws += TOK * DIM_ * 2;                 // 8 MB
    unsigned short* Kh    = (unsigned short*)ws;  ws += TOK * DIM_ * 2;                 // 8 MB
    unsigned short* Vt    = (unsigned short*)ws;  ws += TOK * DIM_ * 2;                 // 8 MB
    unsigned short* Obuf  = (unsigned short*)ws;  ws += TOK * DIM_ * 2;                 // 8 MB
    unsigned short* Opart = (unsigned short*)ws;  ws += (size_t)4 * TOK * DIM_ * 2;     // 32 MB
    float*          lpart = (float*)ws;           ws += (size_t)4 * B_ * NH_ * N_ * 4;  // 1 MB

    const int NW = 3 * DIM_ * DIM_;
    const int NO = DIM_ * DIM_;

    ln_kernel<<<TOK, 256, 0, stream>>>(x, ln_w, ln_b, xn);
    cvt_kernel<<<(NW + NO + 255) / 256, 256, 0, stream>>>(qkv_w, NW, out_w, NO, wq_bf, wo_bf);
    qkv_gemm<<<dim3(TOK / 128, (3 * DIM_) / 128), 512, 0, stream>>>(xn, wq_bf, qkv_b, Qh, Kh, Vt);
    attn_kernel<<<dim3(N_ / 128, B_ * NH_, 4), 256, 0, stream>>>(Qh, Kh, Vt, Opart, lpart);
    combine_kernel<<<(TOK * DIM_) / 4 / 256, 256, 0, stream>>>(Opart, lpart, Obuf);
    out_gemm<<<dim3(TOK / 128, DIM_ / 128), 512, 0, stream>>>(Obuf, wo_bf, out_b, out);
}

// Round 11
// 182.400 us; speedup vs baseline: 1.8788x; 1.8788x over previous
//
#include <hip/hip_runtime.h>

typedef __attribute__((ext_vector_type(8))) short bf16x8;
typedef __attribute__((ext_vector_type(4))) float floatx4;

#define B_    4
#define N_    2048
#define DIM_  512
#define NH_   8
#define HD_   64
#define SCALE_ 0.125f
#define SL2E_ (0.125f * 1.44269504f)   // scale * log2(e), folded into Q

__device__ __forceinline__ unsigned short f32_to_bf16(float f) {
    unsigned int u = __float_as_uint(f);
    u += 0x7FFFu + ((u >> 16) & 1u);   // round-to-nearest-even
    return (unsigned short)(u >> 16);
}

__device__ __forceinline__ float bf16_to_f32(unsigned short u) {
    return __uint_as_float(((unsigned int)u) << 16);
}

__device__ __forceinline__ floatx4 mfma16(bf16x8 a, bf16x8 b, floatx4 c) {
    return __builtin_amdgcn_mfma_f32_16x16x32_bf16(a, b, c, 0, 0, 0);
}

__device__ __forceinline__ floatx4 fzero4() {
    floatx4 z = {0.f, 0.f, 0.f, 0.f};
    return z;
}

// async global->LDS DMA, 16B per lane. lds dest is wave-uniform base; HW adds lane*16.
__device__ __forceinline__ void async16(const unsigned short* g, unsigned short* l) {
    __builtin_amdgcn_global_load_lds((const __attribute__((address_space(1))) void*)g,
                                     (__attribute__((address_space(3))) void*)l,
                                     16, 0, 0);
}

// ---------------- LayerNorm: x[8192][512] fp32 -> xn bf16 ----------------
__global__ __launch_bounds__(256) void ln_kernel(const float* __restrict__ x,
                                                 const float* __restrict__ w,
                                                 const float* __restrict__ b,
                                                 unsigned short* __restrict__ xn) {
    int row = blockIdx.x;
    int tid = threadIdx.x;
    int lane = tid & 63, wid = tid >> 6;
    const float2 v = ((const float2*)(x + (size_t)row * DIM_))[tid];
    float s = v.x + v.y;
    float sq = v.x * v.x + v.y * v.y;
#pragma unroll
    for (int off = 1; off < 64; off <<= 1) {
        s  += __shfl_xor(s, off, 64);
        sq += __shfl_xor(sq, off, 64);
    }
    __shared__ float red[2][4];
    if (lane == 0) { red[0][wid] = s; red[1][wid] = sq; }
    __syncthreads();
    s  = red[0][0] + red[0][1] + red[0][2] + red[0][3];
    sq = red[1][0] + red[1][1] + red[1][2] + red[1][3];
    float mu   = s * (1.f / DIM_);
    float var  = sq * (1.f / DIM_) - mu * mu;
    float rstd = rsqrtf(var + 1e-5f);
    float2 wv = ((const float2*)w)[tid];
    float2 bv = ((const float2*)b)[tid];
    float y0 = (v.x - mu) * rstd * wv.x + bv.x;
    float y1 = (v.y - mu) * rstd * wv.y + bv.y;
    unsigned int pack = (unsigned int)f32_to_bf16(y0) |
                        ((unsigned int)f32_to_bf16(y1) << 16);
    ((unsigned int*)xn)[(size_t)row * (DIM_ / 2) + tid] = pack;
}

// ---------------- fp32 -> bf16 convert (both weight matrices, one launch) ----------------
__global__ __launch_bounds__(256) void cvt_kernel(const float* __restrict__ srcA, int na,
                                                  const float* __restrict__ srcB, int nb,
                                                  unsigned short* __restrict__ dstA,
                                                  unsigned short* __restrict__ dstB) {
    int idx = blockIdx.x * 256 + threadIdx.x;
    if (idx < na)            dstA[idx] = f32_to_bf16(srcA[idx]);
    else if (idx < na + nb)  dstB[idx - na] = f32_to_bf16(srcB[idx - na]);
}

// ======== m97-style LDS-staged GEMM core, 512-thread / 8-wave variant ========
// 128x128 block tile, BK=32, dbuf LDS; wave tile 32x64 (acc[2][4]).
// launch_bounds(512,4): VGPR budget 128 -- NO spill risk (R10 lesson: tighter
// bounds spill the fragment arrays to scratch, ~0.5 GB of HBM traffic).
#define GEMM_CORE512(A_, B_ptr, am0, bn0)                                           \
    __shared__ unsigned short Alds[2][128][32];                                     \
    __shared__ unsigned short Blds[2][128][32];                                     \
    int tid = threadIdx.x, lane = tid & 63, wid = tid >> 6;                         \
    int l15 = lane & 15, quad = lane >> 4;                                          \
    int wmloc = (wid >> 1) * 32, wnloc = (wid & 1) * 64;                            \
    int sr = lane >> 2;                                                             \
    int sc = (lane & 3) * 8;                                                        \
    int srow0 = 16 * wid;                                                           \
    floatx4 acc[2][4];                                                              \
    _Pragma("unroll")                                                               \
    for (int i = 0; i < 2; i++)                                                     \
        _Pragma("unroll")                                                           \
        for (int j = 0; j < 4; j++) acc[i][j] = fzero4();                           \
    int buf = 0;                                                                    \
    async16(A_ + (size_t)(am0 + srow0 + sr) * DIM_ + sc, &Alds[0][srow0][0]);       \
    async16(B_ptr + (size_t)(bn0 + srow0 + sr) * DIM_ + sc, &Blds[0][srow0][0]);    \
    __syncthreads();                                                                \
    for (int t = 0; t < 16; t++) {                                                  \
        if (t < 15) {                                                               \
            int k0 = (t + 1) * 32;                                                  \
            async16(A_ + (size_t)(am0 + srow0 + sr) * DIM_ + k0 + sc,               \
                    &Alds[buf ^ 1][srow0][0]);                                      \
            async16(B_ptr + (size_t)(bn0 + srow0 + sr) * DIM_ + k0 + sc,            \
                    &Blds[buf ^ 1][srow0][0]);                                      \
        }                                                                           \
        bf16x8 av[2], bv[4];                                                        \
        _Pragma("unroll")                                                           \
        for (int i = 0; i < 2; i++)                                                 \
            av[i] = *(const bf16x8*)(&Alds[buf][wmloc + 16 * i + l15][quad * 8]);   \
        _Pragma("unroll")                                                           \
        for (int j = 0; j < 4; j++)                                                 \
            bv[j] = *(const bf16x8*)(&Blds[buf][wnloc + 16 * j + l15][quad * 8]);   \
        _Pragma("unroll")                                                           \
        for (int i = 0; i < 2; i++)                                                 \
            _Pragma("unroll")                                                       \
            for (int j = 0; j < 4; j++)                                             \
                acc[i][j] = mfma16(av[i], bv[j], acc[i][j]);                        \
        __syncthreads();                                                            \
        buf ^= 1;                                                                   \
    }

// ---------------- QKV GEMM: [8192,512] x [1536,512]^T, scatter epilogue ----------------
__global__ __launch_bounds__(512, 4) void qkv_gemm(const unsigned short* __restrict__ A,
                                                   const unsigned short* __restrict__ Bw,
                                                   const float* __restrict__ bias,
                                                   unsigned short* __restrict__ Qh,
                                                   unsigned short* __restrict__ Kh,
                                                   unsigned short* __restrict__ Vt) {
    int am0 = blockIdx.x * 128, bn0 = blockIdx.y * 128;
    GEMM_CORE512(A, Bw, am0, bn0)

    if (bn0 >= 1024) {
        // ---- V path: per-wave LDS transpose -> coalesced Vt[d][t] b128 writes ----
        unsigned short* sc_ = &Alds[0][0][0] + wid * (16 * 40);   // 1280 B/wave
        int m0 = am0 + wmloc;
        int bidx = m0 >> 11;
        int t0 = m0 & 2047;
#pragma unroll
        for (int j = 0; j < 4; j++) {
            float bias_n = bias[bn0 + wnloc + 16 * j + l15];
#pragma unroll
            for (int i = 0; i < 2; i++)
#pragma unroll
                for (int r = 0; r < 4; r++)
                    sc_[l15 * 40 + 16 * i + quad * 4 + r] =
                        f32_to_bf16(acc[i][j][r] + bias_n);
            int nr = lane >> 2;                       // 0..15
            int rem = (bn0 - 1024) + wnloc + 16 * j + nr;
            int head = rem >> 6, d = rem & 63;
            bf16x8 vv = *(const bf16x8*)(sc_ + nr * 40 + (lane & 3) * 8);
            *(bf16x8*)(Vt + ((size_t)(bidx * NH_ + head) * HD_ + d) * N_ +
                       t0 + (lane & 3) * 8) = vv;
        }
    } else {
        // ---- Q/K path (32B-run b16 stores) ----
#pragma unroll
        for (int i = 0; i < 2; i++) {
#pragma unroll
            for (int j = 0; j < 4; j++) {
                int n = bn0 + wnloc + 16 * j + l15;
                float bias_n = bias[n];
                int which = n >> 9;
                int rem = n & 511;
                int head = rem >> 6;
                int d = rem & 63;
#pragma unroll
                for (int r = 0; r < 4; r++) {
                    int m = am0 + wmloc + 16 * i + quad * 4 + r;
                    int b = m >> 11;
                    int t = m & 2047;
                    float val = acc[i][j][r] + bias_n;
                    if (which == 0) {
                        Qh[((size_t)(b * NH_ + head) * N_ + t) * HD_ + d] =
                            f32_to_bf16(val * SL2E_);
                    } else {
                        Kh[((size_t)(b * NH_ + head) * N_ + t) * HD_ + d] =
                            f32_to_bf16(val);
                    }
                }
            }
        }
    }
}

// ---------------- Out projection: [8192,512] x [512,512]^T + bias -> fp32 ----------------
__global__ __launch_bounds__(512, 4) void out_gemm(const unsigned short* __restrict__ A,
                                                   const unsigned short* __restrict__ Bw,
                                                   const float* __restrict__ bias,
                                                   float* __restrict__ out) {
    int am0 = blockIdx.x * 128, bn0 = blockIdx.y * 128;
    GEMM_CORE512(A, Bw, am0, bn0)

#pragma unroll
    for (int i = 0; i < 2; i++) {
#pragma unroll
        for (int j = 0; j < 4; j++) {
            int n = bn0 + wnloc + 16 * j + l15;
            float bias_n = bias[n];
#pragma unroll
            for (int r = 0; r < 4; r++) {
                int m = am0 + wmloc + 16 * i + quad * 4 + r;
                out[(size_t)m * DIM_ + n] = acc[i][j][r] + bias_n;
            }
        }
    }
}

// ---------------- Flash attention, fixed-max softmax, split-KV x2 ----------------
// EXACT R9 version: 71.4 us measured, VGPR 64, no spills. launch_bounds(256,4)
// is this kernel's operating point (R10: tighter bounds -> fragment spill ->
// 0.5 GB scratch traffic -> 3x regression).
__global__ __launch_bounds__(256, 4) void attn_kernel(const unsigned short* __restrict__ Qh,
                                                      const unsigned short* __restrict__ Kh,
                                                      const unsigned short* __restrict__ Vtg,
                                                      unsigned short* __restrict__ Opart,
                                                      float* __restrict__ lpart) {
    int bh = blockIdx.y;
    int b = bh >> 3, head = bh & 7;
    int qt = blockIdx.x;
    int split = blockIdx.z;
    int kv0 = split << 10;                 // 0 or 1024
    int tid = threadIdx.x, lane = tid & 63, w = tid >> 6;
    int l15 = lane & 15, quad = lane >> 4;

    const unsigned short* Qp = Qh + (size_t)bh * N_ * HD_;
    const unsigned short* Kg = Kh + (size_t)bh * N_ * HD_;
    const unsigned short* Vg = Vtg + (size_t)bh * HD_ * N_;

    int q0 = qt * 128 + w * 32;

    bf16x8 aQ[2][2];
#pragma unroll
    for (int mh = 0; mh < 2; mh++) {
        const unsigned short* qrow = Qp + (size_t)(q0 + mh * 16 + l15) * HD_ + quad * 8;
        aQ[mh][0] = *(const bf16x8*)(qrow);
        aQ[mh][1] = *(const bf16x8*)(qrow + 32);
    }

    floatx4 of[2][4];
#pragma unroll
    for (int mh = 0; mh < 2; mh++)
#pragma unroll
        for (int t = 0; t < 4; t++) of[mh][t] = fzero4();
    floatx4 lacc[2];
    lacc[0] = fzero4(); lacc[1] = fzero4();

    const short onebf = (short)0x3F80;   // bf16 1.0
    bf16x8 ones = {onebf, onebf, onebf, onebf, onebf, onebf, onebf, onebf};

    __shared__ unsigned short Kt[64][64];      // 8 KB, XOR-swizzled, single-buffered
    __shared__ unsigned short Vs[64][64];      // 8 KB
    __shared__ unsigned short Pl[4][32][72];   // 18 KB, wave-private, padded

    int srow = lane >> 3;                 // 0..7
    int scol = ((lane & 7) ^ srow) * 8;   // shorts

    int swz0 = (quad ^ (l15 & 7)) * 8;
    int swz1 = ((quad + 4) ^ (l15 & 7)) * 8;

    unsigned short* myP = &Pl[w][0][0];
    for (int kv = kv0; kv < kv0 + 1024; kv += 64) {
#pragma unroll
        for (int i = 0; i < 2; i++) {
            int r0 = 16 * w + 8 * i;
            async16(Kg + (size_t)(kv + r0 + srow) * HD_ + scol, &Kt[r0][0]);
            async16(Vg + (size_t)(r0 + srow) * N_ + kv + scol, &Vs[r0][0]);
        }
        __syncthreads();
        bf16x8 kf[8];
#pragma unroll
        for (int h = 0; h < 4; h++) {
            kf[2 * h]     = *(const bf16x8*)(&Kt[16 * h + l15][swz0]);
            kf[2 * h + 1] = *(const bf16x8*)(&Kt[16 * h + l15][swz1]);
        }
#pragma unroll
        for (int mh = 0; mh < 2; mh++) {
            floatx4 c[4];
#pragma unroll
            for (int h = 0; h < 4; h++) {
                floatx4 cc = fzero4();
                cc = mfma16(aQ[mh][0], kf[2 * h], cc);
                cc = mfma16(aQ[mh][1], kf[2 * h + 1], cc);
                c[h] = cc;
            }
            unsigned short* pw = myP + (mh * 16 + quad * 4) * 72 + l15;
#pragma unroll
            for (int h = 0; h < 4; h++)
#pragma unroll
                for (int r = 0; r < 4; r++)
                    pw[r * 72 + h * 16] = f32_to_bf16(exp2f(c[h][r]));
        }
        bf16x8 vf[8];
#pragma unroll
        for (int t = 0; t < 4; t++) {
            vf[2 * t]     = *(const bf16x8*)(&Vs[16 * t + l15][swz0]);
            vf[2 * t + 1] = *(const bf16x8*)(&Vs[16 * t + l15][swz1]);
        }
#pragma unroll
        for (int mh = 0; mh < 2; mh++) {
            const unsigned short* pr = myP + (mh * 16 + l15) * 72;
            bf16x8 aP0 = *(const bf16x8*)(pr + quad * 8);
            bf16x8 aP1 = *(const bf16x8*)(pr + 32 + quad * 8);
#pragma unroll
            for (int t = 0; t < 4; t++) {
                of[mh][t] = mfma16(aP0, vf[2 * t], of[mh][t]);
                of[mh][t] = mfma16(aP1, vf[2 * t + 1], of[mh][t]);
            }
            lacc[mh] = mfma16(aP0, ones, lacc[mh]);
            lacc[mh] = mfma16(aP1, ones, lacc[mh]);
        }
        __syncthreads();
    }

    unsigned short* Od = Opart + (size_t)split * B_ * N_ * DIM_;
#pragma unroll
    for (int mh = 0; mh < 2; mh++) {
        float inv[4];
#pragma unroll
        for (int r = 0; r < 4; r++) inv[r] = 1.f / lacc[mh][r];
#pragma unroll
        for (int t = 0; t < 4; t++) {
#pragma unroll
            for (int r = 0; r < 4; r++) {
                int t_tok = q0 + mh * 16 + quad * 4 + r;
                int d = 16 * t + l15;
                Od[((size_t)b * N_ + t_tok) * DIM_ + head * HD_ + d] =
                    f32_to_bf16(of[mh][t][r] * inv[r]);
            }
        }
        if (l15 == 0) {
#pragma unroll
            for (int r = 0; r < 4; r++) {
                int t_tok = q0 + mh * 16 + quad * 4 + r;
                lpart[(size_t)split * B_ * NH_ * N_ + (size_t)bh * N_ + t_tok] =
                    lacc[mh][r];
            }
        }
    }
}

// ---------------- combine: Obuf = (l1*O1 + l2*O2)/(l1+l2), bf16 ----------------
__global__ __launch_bounds__(256) void combine_kernel(const unsigned short* __restrict__ Opart,
                                                      const float* __restrict__ lpart,
                                                      unsigned short* __restrict__ Obuf) {
    int idx = blockIdx.x * 256 + threadIdx.x;   // 4-element groups
    int row = idx >> 7;
    int head = (idx & 127) >> 4;
    int b = row >> 11, t = row & 2047;
    size_t li = (size_t)(b * NH_ + head) * N_ + t;
    float l1 = lpart[li];
    float l2 = lpart[(size_t)B_ * NH_ * N_ + li];
    float s = 1.f / (l1 + l2);
    float w1 = l1 * s, w2 = l2 * s;
    const size_t half = (size_t)B_ * N_ * DIM_;
    ushort4 a = ((const ushort4*)Opart)[idx];
    ushort4 c = ((const ushort4*)(Opart + half))[idx];
    ushort4 o;
    o.x = f32_to_bf16(w1 * bf16_to_f32(a.x) + w2 * bf16_to_f32(c.x));
    o.y = f32_to_bf16(w1 * bf16_to_f32(a.y) + w2 * bf16_to_f32(c.y));
    o.z = f32_to_bf16(w1 * bf16_to_f32(a.z) + w2 * bf16_to_f32(c.z));
    o.w = f32_to_bf16(w1 * bf16_to_f32(a.w) + w2 * bf16_to_f32(c.w));
    ((ushort4*)Obuf)[idx] = o;
}

extern "C" void kernel_launch(void* const* d_in, const int* in_sizes, int n_in,
                              void* d_out, int out_size, void* d_ws, size_t ws_size,
                              hipStream_t stream) {
    const float* x     = (const float*)d_in[0];
    const float* ln_w  = (const float*)d_in[1];
    const float* ln_b  = (const float*)d_in[2];
    const float* qkv_w = (const float*)d_in[3];
    const float* qkv_b = (const float*)d_in[4];
    const float* out_w = (const float*)d_in[5];
    const float* out_b = (const float*)d_in[6];
    float* out = (float*)d_out;

    char* ws = (char*)d_ws;
    const size_t TOK = (size_t)B_ * N_;                 // 8192
    unsigned short* xn    = (unsigned short*)ws;  ws += TOK * DIM_ * 2;
    unsigned short* wq_bf = (unsigned short*)ws;  ws += (size_t)3 * DIM_ * DIM_ * 2;
    unsigned short* wo_bf = (unsigned short*)ws;  ws += (size_t)DIM_ * DIM_ * 2;
    unsigned short* Qh    = (unsigned short*)ws;  ws += TOK * DIM_ * 2;
    unsigned short* Kh    = (unsigned short*)ws;  ws += TOK * DIM_ * 2;
    unsigned short* Vt    = (unsigned short*)ws;  ws += TOK * DIM_ * 2;
    unsigned short* Obuf  = (unsigned short*)ws;  ws += TOK * DIM_ * 2;
    unsigned short* Opart = (unsigned short*)ws;  ws += (size_t)2 * TOK * DIM_ * 2;
    float*          lpart = (float*)ws;           ws += (size_t)2 * B_ * NH_ * N_ * 4;

    const int NW = 3 * DIM_ * DIM_;
    const int NO = DIM_ * DIM_;

    ln_kernel<<<TOK, 256, 0, stream>>>(x, ln_w, ln_b, xn);
    cvt_kernel<<<(NW + NO + 255) / 256, 256, 0, stream>>>(qkv_w, NW, out_w, NO, wq_bf, wo_bf);
    qkv_gemm<<<dim3(TOK / 128, (3 * DIM_) / 128), 512, 0, stream>>>(xn, wq_bf, qkv_b, Qh, Kh, Vt);
    attn_kernel<<<dim3(N_ / 128, B_ * NH_, 2), 256, 0, stream>>>(Qh, Kh, Vt, Opart, lpart);
    combine_kernel<<<(TOK * DIM_) / 4 / 256, 256, 0, stream>>>(Opart, lpart, Obuf);
    out_gemm<<<dim3(TOK / 128, DIM_ / 128), 512, 0, stream>>>(Obuf, wo_bf, out_b, out);
}

// Round 12
// 182.314 us; speedup vs baseline: 1.8797x; 1.0005x over previous
//
#include <hip/hip_runtime.h>

typedef __attribute__((ext_vector_type(8))) short bf16x8;
typedef __attribute__((ext_vector_type(4))) float floatx4;

#define B_    4
#define N_    2048
#define DIM_  512
#define NH_   8
#define HD_   64
#define SCALE_ 0.125f
#define SL2E_ (0.125f * 1.44269504f)   // scale * log2(e), folded into Q

__device__ __forceinline__ unsigned short f32_to_bf16(float f) {
    unsigned int u = __float_as_uint(f);
    u += 0x7FFFu + ((u >> 16) & 1u);   // round-to-nearest-even
    return (unsigned short)(u >> 16);
}

__device__ __forceinline__ float bf16_to_f32(unsigned short u) {
    return __uint_as_float(((unsigned int)u) << 16);
}

__device__ __forceinline__ floatx4 mfma16(bf16x8 a, bf16x8 b, floatx4 c) {
    return __builtin_amdgcn_mfma_f32_16x16x32_bf16(a, b, c, 0, 0, 0);
}

__device__ __forceinline__ floatx4 fzero4() {
    floatx4 z = {0.f, 0.f, 0.f, 0.f};
    return z;
}

// async global->LDS DMA, 16B per lane. lds dest is wave-uniform base; HW adds lane*16.
__device__ __forceinline__ void async16(const unsigned short* g, unsigned short* l) {
    __builtin_amdgcn_global_load_lds((const __attribute__((address_space(1))) void*)g,
                                     (__attribute__((address_space(3))) void*)l,
                                     16, 0, 0);
}

// ---------------- LayerNorm: x[8192][512] fp32 -> xn bf16 ----------------
__global__ __launch_bounds__(256) void ln_kernel(const float* __restrict__ x,
                                                 const float* __restrict__ w,
                                                 const float* __restrict__ b,
                                                 unsigned short* __restrict__ xn) {
    int row = blockIdx.x;
    int tid = threadIdx.x;
    int lane = tid & 63, wid = tid >> 6;
    const float2 v = ((const float2*)(x + (size_t)row * DIM_))[tid];
    float s = v.x + v.y;
    float sq = v.x * v.x + v.y * v.y;
#pragma unroll
    for (int off = 1; off < 64; off <<= 1) {
        s  += __shfl_xor(s, off, 64);
        sq += __shfl_xor(sq, off, 64);
    }
    __shared__ float red[2][4];
    if (lane == 0) { red[0][wid] = s; red[1][wid] = sq; }
    __syncthreads();
    s  = red[0][0] + red[0][1] + red[0][2] + red[0][3];
    sq = red[1][0] + red[1][1] + red[1][2] + red[1][3];
    float mu   = s * (1.f / DIM_);
    float var  = sq * (1.f / DIM_) - mu * mu;
    float rstd = rsqrtf(var + 1e-5f);
    float2 wv = ((const float2*)w)[tid];
    float2 bv = ((const float2*)b)[tid];
    float y0 = (v.x - mu) * rstd * wv.x + bv.x;
    float y1 = (v.y - mu) * rstd * wv.y + bv.y;
    unsigned int pack = (unsigned int)f32_to_bf16(y0) |
                        ((unsigned int)f32_to_bf16(y1) << 16);
    ((unsigned int*)xn)[(size_t)row * (DIM_ / 2) + tid] = pack;
}

// ---------------- fp32 -> bf16 convert (both weight matrices, one launch) ----------------
__global__ __launch_bounds__(256) void cvt_kernel(const float* __restrict__ srcA, int na,
                                                  const float* __restrict__ srcB, int nb,
                                                  unsigned short* __restrict__ dstA,
                                                  unsigned short* __restrict__ dstB) {
    int idx = blockIdx.x * 256 + threadIdx.x;
    if (idx < na)            dstA[idx] = f32_to_bf16(srcA[idx]);
    else if (idx < na + nb)  dstB[idx - na] = f32_to_bf16(srcB[idx - na]);
}

// ======== m97-style LDS-staged GEMM core, 512-thread / 8-wave variant ========
// (unchanged from R11 -- launch_bounds(512,4), no spill)
#define GEMM_CORE512(A_, B_ptr, am0, bn0)                                           \
    __shared__ unsigned short Alds[2][128][32];                                     \
    __shared__ unsigned short Blds[2][128][32];                                     \
    int tid = threadIdx.x, lane = tid & 63, wid = tid >> 6;                         \
    int l15 = lane & 15, quad = lane >> 4;                                          \
    int wmloc = (wid >> 1) * 32, wnloc = (wid & 1) * 64;                            \
    int sr = lane >> 2;                                                             \
    int sc = (lane & 3) * 8;                                                        \
    int srow0 = 16 * wid;                                                           \
    floatx4 acc[2][4];                                                              \
    _Pragma("unroll")                                                               \
    for (int i = 0; i < 2; i++)                                                     \
        _Pragma("unroll")                                                           \
        for (int j = 0; j < 4; j++) acc[i][j] = fzero4();                           \
    int buf = 0;                                                                    \
    async16(A_ + (size_t)(am0 + srow0 + sr) * DIM_ + sc, &Alds[0][srow0][0]);       \
    async16(B_ptr + (size_t)(bn0 + srow0 + sr) * DIM_ + sc, &Blds[0][srow0][0]);    \
    __syncthreads();                                                                \
    for (int t = 0; t < 16; t++) {                                                  \
        if (t < 15) {                                                               \
            int k0 = (t + 1) * 32;                                                  \
            async16(A_ + (size_t)(am0 + srow0 + sr) * DIM_ + k0 + sc,               \
                    &Alds[buf ^ 1][srow0][0]);                                      \
            async16(B_ptr + (size_t)(bn0 + srow0 + sr) * DIM_ + k0 + sc,            \
                    &Blds[buf ^ 1][srow0][0]);                                      \
        }                                                                           \
        bf16x8 av[2], bv[4];                                                        \
        _Pragma("unroll")                                                           \
        for (int i = 0; i < 2; i++)                                                 \
            av[i] = *(const bf16x8*)(&Alds[buf][wmloc + 16 * i + l15][quad * 8]);   \
        _Pragma("unroll")                                                           \
        for (int j = 0; j < 4; j++)                                                 \
            bv[j] = *(const bf16x8*)(&Blds[buf][wnloc + 16 * j + l15][quad * 8]);   \
        _Pragma("unroll")                                                           \
        for (int i = 0; i < 2; i++)                                                 \
            _Pragma("unroll")                                                       \
            for (int j = 0; j < 4; j++)                                             \
                acc[i][j] = mfma16(av[i], bv[j], acc[i][j]);                        \
        __syncthreads();                                                            \
        buf ^= 1;                                                                   \
    }

// ---------------- QKV GEMM: [8192,512] x [1536,512]^T, scatter epilogue ----------------
__global__ __launch_bounds__(512, 4) void qkv_gemm(const unsigned short* __restrict__ A,
                                                   const unsigned short* __restrict__ Bw,
                                                   const float* __restrict__ bias,
                                                   unsigned short* __restrict__ Qh,
                                                   unsigned short* __restrict__ Kh,
                                                   unsigned short* __restrict__ Vt) {
    int am0 = blockIdx.x * 128, bn0 = blockIdx.y * 128;
    GEMM_CORE512(A, Bw, am0, bn0)

    if (bn0 >= 1024) {
        // ---- V path: per-wave LDS transpose -> coalesced Vt[d][t] b128 writes ----
        unsigned short* sc_ = &Alds[0][0][0] + wid * (16 * 40);   // 1280 B/wave
        int m0 = am0 + wmloc;
        int bidx = m0 >> 11;
        int t0 = m0 & 2047;
#pragma unroll
        for (int j = 0; j < 4; j++) {
            float bias_n = bias[bn0 + wnloc + 16 * j + l15];
#pragma unroll
            for (int i = 0; i < 2; i++)
#pragma unroll
                for (int r = 0; r < 4; r++)
                    sc_[l15 * 40 + 16 * i + quad * 4 + r] =
                        f32_to_bf16(acc[i][j][r] + bias_n);
            int nr = lane >> 2;                       // 0..15
            int rem = (bn0 - 1024) + wnloc + 16 * j + nr;
            int head = rem >> 6, d = rem & 63;
            bf16x8 vv = *(const bf16x8*)(sc_ + nr * 40 + (lane & 3) * 8);
            *(bf16x8*)(Vt + ((size_t)(bidx * NH_ + head) * HD_ + d) * N_ +
                       t0 + (lane & 3) * 8) = vv;
        }
    } else {
        // ---- Q/K path (32B-run b16 stores) ----
#pragma unroll
        for (int i = 0; i < 2; i++) {
#pragma unroll
            for (int j = 0; j < 4; j++) {
                int n = bn0 + wnloc + 16 * j + l15;
                float bias_n = bias[n];
                int which = n >> 9;
                int rem = n & 511;
                int head = rem >> 6;
                int d = rem & 63;
#pragma unroll
                for (int r = 0; r < 4; r++) {
                    int m = am0 + wmloc + 16 * i + quad * 4 + r;
                    int b = m >> 11;
                    int t = m & 2047;
                    float val = acc[i][j][r] + bias_n;
                    if (which == 0) {
                        Qh[((size_t)(b * NH_ + head) * N_ + t) * HD_ + d] =
                            f32_to_bf16(val * SL2E_);
                    } else {
                        Kh[((size_t)(b * NH_ + head) * N_ + t) * HD_ + d] =
                            f32_to_bf16(val);
                    }
                }
            }
        }
    }
}

// ---------------- Fused combine + out projection ----------------
// A = combine(Opart0, Opart1, lpart) staged MANUALLY into padded LDS (stride 36,
// manual b128 writes aren't DMA-constrained); B via async16. Deletes the
// combine kernel + Obuf 16 MB round trip. Block tile 64x128, 256 thr / 4 waves,
// grid (128,4) = 512 blocks -> 2 blocks/CU (old out_gemm had 1).
__global__ __launch_bounds__(256, 4) void out_gemm_fused(const unsigned short* __restrict__ Opart,
                                                         const float* __restrict__ lpart,
                                                         const unsigned short* __restrict__ Bw,
                                                         const float* __restrict__ bias,
                                                         float* __restrict__ out) {
    __shared__ unsigned short Alds[2][64][36];    // padded, manual writes
    __shared__ unsigned short Blds[2][128][32];   // DMA-staged
    int tid = threadIdx.x, lane = tid & 63, wid = tid >> 6;
    int l15 = lane & 15, quad = lane >> 4;
    int wmloc = (wid >> 1) * 32, wnloc = (wid & 1) * 64;
    int am0 = blockIdx.x * 64, bn0 = blockIdx.y * 128;

    // A-staging geometry: thread covers row arow (0..63), cols ac8*8..+8 of the k-tile
    int arow = tid >> 2;
    int ac8 = (tid & 3) * 8;
    int token = am0 + arow;                    // never crosses batch boundary (2048%64==0)
    int bb = token >> 11;
    const size_t LSTR = (size_t)B_ * NH_ * N_;
    const size_t OSTR = (size_t)B_ * N_ * DIM_;
    const unsigned short* arow0 = Opart + (size_t)token * DIM_;   // split 0
    const unsigned short* arow1 = arow0 + OSTR;                   // split 1

    // B-staging geometry (async16): 128 rows x 32 k per step, 2 DMA/thread
    int sr = lane >> 2;
    int sc = (lane & 3) * 8;

    floatx4 acc[2][4];
#pragma unroll
    for (int i = 0; i < 2; i++)
#pragma unroll
        for (int j = 0; j < 4; j++) acc[i][j] = fzero4();

#define STAGE_A(BUF, T)                                                         \
    {                                                                           \
        int k0 = (T) * 32;                                                      \
        int head = k0 >> 6;                                                     \
        size_t li = (size_t)(bb * NH_ + head) * N_ + (token & 2047);            \
        float l1 = lpart[li];                                                   \
        float l2 = lpart[LSTR + li];                                            \
        float inv = 1.f / (l1 + l2);                                            \
        float w1 = l1 * inv, w2 = l2 * inv;                                     \
        bf16x8 o0 = *(const bf16x8*)(arow0 + k0 + ac8);                         \
        bf16x8 o1 = *(const bf16x8*)(arow1 + k0 + ac8);                         \
        bf16x8 pk;                                                              \
        _Pragma("unroll")                                                       \
        for (int e = 0; e < 8; e++)                                             \
            pk[e] = (short)f32_to_bf16(                                         \
                w1 * bf16_to_f32((unsigned short)o0[e]) +                       \
                w2 * bf16_to_f32((unsigned short)o1[e]));                       \
        *(bf16x8*)(&Alds[BUF][arow][ac8]) = pk;                                 \
    }

#define STAGE_B(BUF, T)                                                         \
    {                                                                           \
        int k0 = (T) * 32;                                                      \
        _Pragma("unroll")                                                       \
        for (int i = 0; i < 2; i++) {                                           \
            int r0 = 32 * wid + 16 * i;                                         \
            async16(Bw + (size_t)(bn0 + r0 + sr) * DIM_ + k0 + sc,              \
                    &Blds[BUF][r0][0]);                                         \
        }                                                                       \
    }

    STAGE_B(0, 0)
    STAGE_A(0, 0)
    __syncthreads();
    int buf = 0;
    for (int t = 0; t < 16; t++) {
        if (t < 15) {
            STAGE_B(buf ^ 1, t + 1)
            STAGE_A(buf ^ 1, t + 1)
        }
        bf16x8 av[2], bv[4];
#pragma unroll
        for (int i = 0; i < 2; i++)
            av[i] = *(const bf16x8*)(&Alds[buf][wmloc + 16 * i + l15][quad * 8]);
#pragma unroll
        for (int j = 0; j < 4; j++)
            bv[j] = *(const bf16x8*)(&Blds[buf][wnloc + 16 * j + l15][quad * 8]);
#pragma unroll
        for (int i = 0; i < 2; i++)
#pragma unroll
            for (int j = 0; j < 4; j++)
                acc[i][j] = mfma16(av[i], bv[j], acc[i][j]);
        __syncthreads();
        buf ^= 1;
    }
#undef STAGE_A
#undef STAGE_B

#pragma unroll
    for (int i = 0; i < 2; i++) {
#pragma unroll
        for (int j = 0; j < 4; j++) {
            int n = bn0 + wnloc + 16 * j + l15;
            float bias_n = bias[n];
#pragma unroll
            for (int r = 0; r < 4; r++) {
                int m = am0 + wmloc + 16 * i + quad * 4 + r;
                out[(size_t)m * DIM_ + n] = acc[i][j][r] + bias_n;
            }
        }
    }
}

// ---------------- Flash attention, fixed-max softmax, split-KV x2 ----------------
// EXACT R9/R11 version: 71.4-72.4 us measured, VGPR 64, no spills.
__global__ __launch_bounds__(256, 4) void attn_kernel(const unsigned short* __restrict__ Qh,
                                                      const unsigned short* __restrict__ Kh,
                                                      const unsigned short* __restrict__ Vtg,
                                                      unsigned short* __restrict__ Opart,
                                                      float* __restrict__ lpart) {
    int bh = blockIdx.y;
    int b = bh >> 3, head = bh & 7;
    int qt = blockIdx.x;
    int split = blockIdx.z;
    int kv0 = split << 10;                 // 0 or 1024
    int tid = threadIdx.x, lane = tid & 63, w = tid >> 6;
    int l15 = lane & 15, quad = lane >> 4;

    const unsigned short* Qp = Qh + (size_t)bh * N_ * HD_;
    const unsigned short* Kg = Kh + (size_t)bh * N_ * HD_;
    const unsigned short* Vg = Vtg + (size_t)bh * HD_ * N_;

    int q0 = qt * 128 + w * 32;

    bf16x8 aQ[2][2];
#pragma unroll
    for (int mh = 0; mh < 2; mh++) {
        const unsigned short* qrow = Qp + (size_t)(q0 + mh * 16 + l15) * HD_ + quad * 8;
        aQ[mh][0] = *(const bf16x8*)(qrow);
        aQ[mh][1] = *(const bf16x8*)(qrow + 32);
    }

    floatx4 of[2][4];
#pragma unroll
    for (int mh = 0; mh < 2; mh++)
#pragma unroll
        for (int t = 0; t < 4; t++) of[mh][t] = fzero4();
    floatx4 lacc[2];
    lacc[0] = fzero4(); lacc[1] = fzero4();

    const short onebf = (short)0x3F80;   // bf16 1.0
    bf16x8 ones = {onebf, onebf, onebf, onebf, onebf, onebf, onebf, onebf};

    __shared__ unsigned short Kt[64][64];      // 8 KB, XOR-swizzled, single-buffered
    __shared__ unsigned short Vs[64][64];      // 8 KB
    __shared__ unsigned short Pl[4][32][72];   // 18 KB, wave-private, padded

    int srow = lane >> 3;                 // 0..7
    int scol = ((lane & 7) ^ srow) * 8;   // shorts

    int swz0 = (quad ^ (l15 & 7)) * 8;
    int swz1 = ((quad + 4) ^ (l15 & 7)) * 8;

    unsigned short* myP = &Pl[w][0][0];
    for (int kv = kv0; kv < kv0 + 1024; kv += 64) {
#pragma unroll
        for (int i = 0; i < 2; i++) {
            int r0 = 16 * w + 8 * i;
            async16(Kg + (size_t)(kv + r0 + srow) * HD_ + scol, &Kt[r0][0]);
            async16(Vg + (size_t)(r0 + srow) * N_ + kv + scol, &Vs[r0][0]);
        }
        __syncthreads();
        bf16x8 kf[8];
#pragma unroll
        for (int h = 0; h < 4; h++) {
            kf[2 * h]     = *(const bf16x8*)(&Kt[16 * h + l15][swz0]);
            kf[2 * h + 1] = *(const bf16x8*)(&Kt[16 * h + l15][swz1]);
        }
#pragma unroll
        for (int mh = 0; mh < 2; mh++) {
            floatx4 c[4];
#pragma unroll
            for (int h = 0; h < 4; h++) {
                floatx4 cc = fzero4();
                cc = mfma16(aQ[mh][0], kf[2 * h], cc);
                cc = mfma16(aQ[mh][1], kf[2 * h + 1], cc);
                c[h] = cc;
            }
            unsigned short* pw = myP + (mh * 16 + quad * 4) * 72 + l15;
#pragma unroll
            for (int h = 0; h < 4; h++)
#pragma unroll
                for (int r = 0; r < 4; r++)
                    pw[r * 72 + h * 16] = f32_to_bf16(exp2f(c[h][r]));
        }
        bf16x8 vf[8];
#pragma unroll
        for (int t = 0; t < 4; t++) {
            vf[2 * t]     = *(const bf16x8*)(&Vs[16 * t + l15][swz0]);
            vf[2 * t + 1] = *(const bf16x8*)(&Vs[16 * t + l15][swz1]);
        }
#pragma unroll
        for (int mh = 0; mh < 2; mh++) {
            const unsigned short* pr = myP + (mh * 16 + l15) * 72;
            bf16x8 aP0 = *(const bf16x8*)(pr + quad * 8);
            bf16x8 aP1 = *(const bf16x8*)(pr + 32 + quad * 8);
#pragma unroll
            for (int t = 0; t < 4; t++) {
                of[mh][t] = mfma16(aP0, vf[2 * t], of[mh][t]);
                of[mh][t] = mfma16(aP1, vf[2 * t + 1], of[mh][t]);
            }
            lacc[mh] = mfma16(aP0, ones, lacc[mh]);
            lacc[mh] = mfma16(aP1, ones, lacc[mh]);
        }
        __syncthreads();
    }

    unsigned short* Od = Opart + (size_t)split * B_ * N_ * DIM_;
#pragma unroll
    for (int mh = 0; mh < 2; mh++) {
        float inv[4];
#pragma unroll
        for (int r = 0; r < 4; r++) inv[r] = 1.f / lacc[mh][r];
#pragma unroll
        for (int t = 0; t < 4; t++) {
#pragma unroll
            for (int r = 0; r < 4; r++) {
                int t_tok = q0 + mh * 16 + quad * 4 + r;
                int d = 16 * t + l15;
                Od[((size_t)b * N_ + t_tok) * DIM_ + head * HD_ + d] =
                    f32_to_bf16(of[mh][t][r] * inv[r]);
            }
        }
        if (l15 == 0) {
#pragma unroll
            for (int r = 0; r < 4; r++) {
                int t_tok = q0 + mh * 16 + quad * 4 + r;
                lpart[(size_t)split * B_ * NH_ * N_ + (size_t)bh * N_ + t_tok] =
                    lacc[mh][r];
            }
        }
    }
}

extern "C" void kernel_launch(void* const* d_in, const int* in_sizes, int n_in,
                              void* d_out, int out_size, void* d_ws, size_t ws_size,
                              hipStream_t stream) {
    const float* x     = (const float*)d_in[0];
    const float* ln_w  = (const float*)d_in[1];
    const float* ln_b  = (const float*)d_in[2];
    const float* qkv_w = (const float*)d_in[3];
    const float* qkv_b = (const float*)d_in[4];
    const float* out_w = (const float*)d_in[5];
    const float* out_b = (const float*)d_in[6];
    float* out = (float*)d_out;

    char* ws = (char*)d_ws;
    const size_t TOK = (size_t)B_ * N_;                 // 8192
    unsigned short* xn    = (unsigned short*)ws;  ws += TOK * DIM_ * 2;
    unsigned short* wq_bf = (unsigned short*)ws;  ws += (size_t)3 * DIM_ * DIM_ * 2;
    unsigned short* wo_bf = (unsigned short*)ws;  ws += (size_t)DIM_ * DIM_ * 2;
    unsigned short* Qh    = (unsigned short*)ws;  ws += TOK * DIM_ * 2;
    unsigned short* Kh    = (unsigned short*)ws;  ws += TOK * DIM_ * 2;
    unsigned short* Vt    = (unsigned short*)ws;  ws += TOK * DIM_ * 2;
    unsigned short* Opart = (unsigned short*)ws;  ws += (size_t)2 * TOK * DIM_ * 2;
    float*          lpart = (float*)ws;           ws += (size_t)2 * B_ * NH_ * N_ * 4;

    const int NW = 3 * DIM_ * DIM_;
    const int NO = DIM_ * DIM_;

    ln_kernel<<<TOK, 256, 0, stream>>>(x, ln_w, ln_b, xn);
    cvt_kernel<<<(NW + NO + 255) / 256, 256, 0, stream>>>(qkv_w, NW, out_w, NO, wq_bf, wo_bf);
    qkv_gemm<<<dim3(TOK / 128, (3 * DIM_) / 128), 512, 0, stream>>>(xn, wq_bf, qkv_b, Qh, Kh, Vt);
    attn_kernel<<<dim3(N_ / 128, B_ * NH_, 2), 256, 0, stream>>>(Qh, Kh, Vt, Opart, lpart);
    out_gemm_fused<<<dim3(TOK / 64, DIM_ / 128), 256, 0, stream>>>(Opart, lpart, wo_bf, out_b, out);
}

// Round 13
// 174.394 us; speedup vs baseline: 1.9651x; 1.0454x over previous
//
#include <hip/hip_runtime.h>

typedef __attribute__((ext_vector_type(8))) short bf16x8;
typedef __attribute__((ext_vector_type(4))) float floatx4;

#define B_    4
#define N_    2048
#define DIM_  512
#define NH_   8
#define HD_   64
#define SCALE_ 0.125f
#define SL2E_ (0.125f * 1.44269504f)   // scale * log2(e), folded into Q

// round-half-up bf16 convert: 2 VALU ops (vs 5 for RNE; differs only on exact
// ties, prob ~2^-24 on random data). Measured: attn VALU stream is ~40% bf16
// converts -- this is the cheap 60% of that cost.
__device__ __forceinline__ unsigned short f32_to_bf16(float f) {
    return (unsigned short)((__float_as_uint(f) + 0x8000u) >> 16);
}

__device__ __forceinline__ float bf16_to_f32(unsigned short u) {
    return __uint_as_float(((unsigned int)u) << 16);
}

__device__ __forceinline__ floatx4 mfma16(bf16x8 a, bf16x8 b, floatx4 c) {
    return __builtin_amdgcn_mfma_f32_16x16x32_bf16(a, b, c, 0, 0, 0);
}

__device__ __forceinline__ floatx4 fzero4() {
    floatx4 z = {0.f, 0.f, 0.f, 0.f};
    return z;
}

// async global->LDS DMA, 16B per lane. lds dest is wave-uniform base; HW adds lane*16.
__device__ __forceinline__ void async16(const unsigned short* g, unsigned short* l) {
    __builtin_amdgcn_global_load_lds((const __attribute__((address_space(1))) void*)g,
                                     (__attribute__((address_space(3))) void*)l,
                                     16, 0, 0);
}

// ---------------- LayerNorm: wave-per-row, no LDS, no barrier ----------------
// 2048 blocks x 4 waves; each wave owns one row; lane holds 8 consecutive floats.
__global__ __launch_bounds__(256) void ln_kernel(const float* __restrict__ x,
                                                 const float* __restrict__ w,
                                                 const float* __restrict__ b,
                                                 unsigned short* __restrict__ xn) {
    int wv = threadIdx.x >> 6;
    int lane = threadIdx.x & 63;
    int row = blockIdx.x * 4 + wv;
    const float4* xr = (const float4*)(x + (size_t)row * DIM_);
    float4 v0 = xr[lane * 2];
    float4 v1 = xr[lane * 2 + 1];
    float s  = (v0.x + v0.y + v0.z + v0.w) + (v1.x + v1.y + v1.z + v1.w);
    float sq = v0.x*v0.x + v0.y*v0.y + v0.z*v0.z + v0.w*v0.w +
               v1.x*v1.x + v1.y*v1.y + v1.z*v1.z + v1.w*v1.w;
#pragma unroll
    for (int off = 1; off < 64; off <<= 1) {
        s  += __shfl_xor(s, off, 64);
        sq += __shfl_xor(sq, off, 64);
    }
    float mu   = s * (1.f / DIM_);
    float var  = sq * (1.f / DIM_) - mu * mu;
    float rstd = rsqrtf(var + 1e-5f);
    float4 w0 = ((const float4*)w)[lane * 2];
    float4 w1 = ((const float4*)w)[lane * 2 + 1];
    float4 b0 = ((const float4*)b)[lane * 2];
    float4 b1 = ((const float4*)b)[lane * 2 + 1];
    float y[8];
    y[0] = (v0.x - mu) * rstd * w0.x + b0.x;
    y[1] = (v0.y - mu) * rstd * w0.y + b0.y;
    y[2] = (v0.z - mu) * rstd * w0.z + b0.z;
    y[3] = (v0.w - mu) * rstd * w0.w + b0.w;
    y[4] = (v1.x - mu) * rstd * w1.x + b1.x;
    y[5] = (v1.y - mu) * rstd * w1.y + b1.y;
    y[6] = (v1.z - mu) * rstd * w1.z + b1.z;
    y[7] = (v1.w - mu) * rstd * w1.w + b1.w;
    uint4 pk;
    pk.x = (unsigned int)f32_to_bf16(y[0]) | ((unsigned int)f32_to_bf16(y[1]) << 16);
    pk.y = (unsigned int)f32_to_bf16(y[2]) | ((unsigned int)f32_to_bf16(y[3]) << 16);
    pk.z = (unsigned int)f32_to_bf16(y[4]) | ((unsigned int)f32_to_bf16(y[5]) << 16);
    pk.w = (unsigned int)f32_to_bf16(y[6]) | ((unsigned int)f32_to_bf16(y[7]) << 16);
    ((uint4*)(xn + (size_t)row * DIM_))[lane] = pk;
}

// ---------------- fp32 -> bf16 convert (both weight matrices, one launch) ----------------
__global__ __launch_bounds__(256) void cvt_kernel(const float* __restrict__ srcA, int na,
                                                  const float* __restrict__ srcB, int nb,
                                                  unsigned short* __restrict__ dstA,
                                                  unsigned short* __restrict__ dstB) {
    int idx = blockIdx.x * 256 + threadIdx.x;
    if (idx < na)            dstA[idx] = f32_to_bf16(srcA[idx]);
    else if (idx < na + nb)  dstB[idx - na] = f32_to_bf16(srcB[idx - na]);
}

// ======== m97-style LDS-staged GEMM core, 512-thread / 8-wave variant ========
// (unchanged from R11/R12 -- launch_bounds(512,4), no spill)
#define GEMM_CORE512(A_, B_ptr, am0, bn0)                                           \
    __shared__ unsigned short Alds[2][128][32];                                     \
    __shared__ unsigned short Blds[2][128][32];                                     \
    int tid = threadIdx.x, lane = tid & 63, wid = tid >> 6;                         \
    int l15 = lane & 15, quad = lane >> 4;                                          \
    int wmloc = (wid >> 1) * 32, wnloc = (wid & 1) * 64;                            \
    int sr = lane >> 2;                                                             \
    int sc = (lane & 3) * 8;                                                        \
    int srow0 = 16 * wid;                                                           \
    floatx4 acc[2][4];                                                              \
    _Pragma("unroll")                                                               \
    for (int i = 0; i < 2; i++)                                                     \
        _Pragma("unroll")                                                           \
        for (int j = 0; j < 4; j++) acc[i][j] = fzero4();                           \
    int buf = 0;                                                                    \
    async16(A_ + (size_t)(am0 + srow0 + sr) * DIM_ + sc, &Alds[0][srow0][0]);       \
    async16(B_ptr + (size_t)(bn0 + srow0 + sr) * DIM_ + sc, &Blds[0][srow0][0]);    \
    __syncthreads();                                                                \
    for (int t = 0; t < 16; t++) {                                                  \
        if (t < 15) {                                                               \
            int k0 = (t + 1) * 32;                                                  \
            async16(A_ + (size_t)(am0 + srow0 + sr) * DIM_ + k0 + sc,               \
                    &Alds[buf ^ 1][srow0][0]);                                      \
            async16(B_ptr + (size_t)(bn0 + srow0 + sr) * DIM_ + k0 + sc,            \
                    &Blds[buf ^ 1][srow0][0]);                                      \
        }                                                                           \
        bf16x8 av[2], bv[4];                                                        \
        _Pragma("unroll")                                                           \
        for (int i = 0; i < 2; i++)                                                 \
            av[i] = *(const bf16x8*)(&Alds[buf][wmloc + 16 * i + l15][quad * 8]);   \
        _Pragma("unroll")                                                           \
        for (int j = 0; j < 4; j++)                                                 \
            bv[j] = *(const bf16x8*)(&Blds[buf][wnloc + 16 * j + l15][quad * 8]);   \
        _Pragma("unroll")                                                           \
        for (int i = 0; i < 2; i++)                                                 \
            _Pragma("unroll")                                                       \
            for (int j = 0; j < 4; j++)                                             \
                acc[i][j] = mfma16(av[i], bv[j], acc[i][j]);                        \
        __syncthreads();                                                            \
        buf ^= 1;                                                                   \
    }

// ---------------- QKV GEMM: [8192,512] x [1536,512]^T, scatter epilogue ----------------
__global__ __launch_bounds__(512, 4) void qkv_gemm(const unsigned short* __restrict__ A,
                                                   const unsigned short* __restrict__ Bw,
                                                   const float* __restrict__ bias,
                                                   unsigned short* __restrict__ Qh,
                                                   unsigned short* __restrict__ Kh,
                                                   unsigned short* __restrict__ Vt) {
    int am0 = blockIdx.x * 128, bn0 = blockIdx.y * 128;
    GEMM_CORE512(A, Bw, am0, bn0)

    if (bn0 >= 1024) {
        // ---- V path: per-wave LDS transpose -> coalesced Vt[d][t] b128 writes ----
        unsigned short* sc_ = &Alds[0][0][0] + wid * (16 * 40);   // 1280 B/wave
        int m0 = am0 + wmloc;
        int bidx = m0 >> 11;
        int t0 = m0 & 2047;
#pragma unroll
        for (int j = 0; j < 4; j++) {
            float bias_n = bias[bn0 + wnloc + 16 * j + l15];
#pragma unroll
            for (int i = 0; i < 2; i++)
#pragma unroll
                for (int r = 0; r < 4; r++)
                    sc_[l15 * 40 + 16 * i + quad * 4 + r] =
                        f32_to_bf16(acc[i][j][r] + bias_n);
            int nr = lane >> 2;                       // 0..15
            int rem = (bn0 - 1024) + wnloc + 16 * j + nr;
            int head = rem >> 6, d = rem & 63;
            bf16x8 vv = *(const bf16x8*)(sc_ + nr * 40 + (lane & 3) * 8);
            *(bf16x8*)(Vt + ((size_t)(bidx * NH_ + head) * HD_ + d) * N_ +
                       t0 + (lane & 3) * 8) = vv;
        }
    } else {
        // ---- Q/K path (32B-run b16 stores) ----
#pragma unroll
        for (int i = 0; i < 2; i++) {
#pragma unroll
            for (int j = 0; j < 4; j++) {
                int n = bn0 + wnloc + 16 * j + l15;
                float bias_n = bias[n];
                int which = n >> 9;
                int rem = n & 511;
                int head = rem >> 6;
                int d = rem & 63;
#pragma unroll
                for (int r = 0; r < 4; r++) {
                    int m = am0 + wmloc + 16 * i + quad * 4 + r;
                    int b = m >> 11;
                    int t = m & 2047;
                    float val = acc[i][j][r] + bias_n;
                    if (which == 0) {
                        Qh[((size_t)(b * NH_ + head) * N_ + t) * HD_ + d] =
                            f32_to_bf16(val * SL2E_);
                    } else {
                        Kh[((size_t)(b * NH_ + head) * N_ + t) * HD_ + d] =
                            f32_to_bf16(val);
                    }
                }
            }
        }
    }
}

// ---------------- Fused combine + out projection (unchanged from R12) ----------------
__global__ __launch_bounds__(256, 4) void out_gemm_fused(const unsigned short* __restrict__ Opart,
                                                         const float* __restrict__ lpart,
                                                         const unsigned short* __restrict__ Bw,
                                                         const float* __restrict__ bias,
                                                         float* __restrict__ out) {
    __shared__ unsigned short Alds[2][64][36];    // padded, manual writes
    __shared__ unsigned short Blds[2][128][32];   // DMA-staged
    int tid = threadIdx.x, lane = tid & 63, wid = tid >> 6;
    int l15 = lane & 15, quad = lane >> 4;
    int wmloc = (wid >> 1) * 32, wnloc = (wid & 1) * 64;
    int am0 = blockIdx.x * 64, bn0 = blockIdx.y * 128;

    int arow = tid >> 2;
    int ac8 = (tid & 3) * 8;
    int token = am0 + arow;
    int bb = token >> 11;
    const size_t LSTR = (size_t)B_ * NH_ * N_;
    const size_t OSTR = (size_t)B_ * N_ * DIM_;
    const unsigned short* arow0 = Opart + (size_t)token * DIM_;
    const unsigned short* arow1 = arow0 + OSTR;

    int sr = lane >> 2;
    int sc = (lane & 3) * 8;

    floatx4 acc[2][4];
#pragma unroll
    for (int i = 0; i < 2; i++)
#pragma unroll
        for (int j = 0; j < 4; j++) acc[i][j] = fzero4();

#define STAGE_A(BUF, T)                                                         \
    {                                                                           \
        int k0 = (T) * 32;                                                      \
        int head = k0 >> 6;                                                     \
        size_t li = (size_t)(bb * NH_ + head) * N_ + (token & 2047);            \
        float l1 = lpart[li];                                                   \
        float l2 = lpart[LSTR + li];                                            \
        float inv = 1.f / (l1 + l2);                                            \
        float w1 = l1 * inv, w2 = l2 * inv;                                     \
        bf16x8 o0 = *(const bf16x8*)(arow0 + k0 + ac8);                         \
        bf16x8 o1 = *(const bf16x8*)(arow1 + k0 + ac8);                         \
        bf16x8 pk;                                                              \
        _Pragma("unroll")                                                       \
        for (int e = 0; e < 8; e++)                                             \
            pk[e] = (short)f32_to_bf16(                                         \
                w1 * bf16_to_f32((unsigned short)o0[e]) +                       \
                w2 * bf16_to_f32((unsigned short)o1[e]));                       \
        *(bf16x8*)(&Alds[BUF][arow][ac8]) = pk;                                 \
    }

#define STAGE_B(BUF, T)                                                         \
    {                                                                           \
        int k0 = (T) * 32;                                                      \
        _Pragma("unroll")                                                       \
        for (int i = 0; i < 2; i++) {                                           \
            int r0 = 32 * wid + 16 * i;                                         \
            async16(Bw + (size_t)(bn0 + r0 + sr) * DIM_ + k0 + sc,              \
                    &Blds[BUF][r0][0]);                                         \
        }                                                                       \
    }

    STAGE_B(0, 0)
    STAGE_A(0, 0)
    __syncthreads();
    int buf = 0;
    for (int t = 0; t < 16; t++) {
        if (t < 15) {
            STAGE_B(buf ^ 1, t + 1)
            STAGE_A(buf ^ 1, t + 1)
        }
        bf16x8 av[2], bv[4];
#pragma unroll
        for (int i = 0; i < 2; i++)
            av[i] = *(const bf16x8*)(&Alds[buf][wmloc + 16 * i + l15][quad * 8]);
#pragma unroll
        for (int j = 0; j < 4; j++)
            bv[j] = *(const bf16x8*)(&Blds[buf][wnloc + 16 * j + l15][quad * 8]);
#pragma unroll
        for (int i = 0; i < 2; i++)
#pragma unroll
            for (int j = 0; j < 4; j++)
                acc[i][j] = mfma16(av[i], bv[j], acc[i][j]);
        __syncthreads();
        buf ^= 1;
    }
#undef STAGE_A
#undef STAGE_B

#pragma unroll
    for (int i = 0; i < 2; i++) {
#pragma unroll
        for (int j = 0; j < 4; j++) {
            int n = bn0 + wnloc + 16 * j + l15;
            float bias_n = bias[n];
#pragma unroll
            for (int r = 0; r < 4; r++) {
                int m = am0 + wmloc + 16 * i + quad * 4 + r;
                out[(size_t)m * DIM_ + n] = acc[i][j][r] + bias_n;
            }
        }
    }
}

// ---------------- Flash attention, fixed-max softmax, split-KV x2 ----------------
// R9/R11 structure (71.4-72.4 us); only change: cheap bf16 convert for P.
__global__ __launch_bounds__(256, 4) void attn_kernel(const unsigned short* __restrict__ Qh,
                                                      const unsigned short* __restrict__ Kh,
                                                      const unsigned short* __restrict__ Vtg,
                                                      unsigned short* __restrict__ Opart,
                                                      float* __restrict__ lpart) {
    int bh = blockIdx.y;
    int b = bh >> 3, head = bh & 7;
    int qt = blockIdx.x;
    int split = blockIdx.z;
    int kv0 = split << 10;                 // 0 or 1024
    int tid = threadIdx.x, lane = tid & 63, w = tid >> 6;
    int l15 = lane & 15, quad = lane >> 4;

    const unsigned short* Qp = Qh + (size_t)bh * N_ * HD_;
    const unsigned short* Kg = Kh + (size_t)bh * N_ * HD_;
    const unsigned short* Vg = Vtg + (size_t)bh * HD_ * N_;

    int q0 = qt * 128 + w * 32;

    bf16x8 aQ[2][2];
#pragma unroll
    for (int mh = 0; mh < 2; mh++) {
        const unsigned short* qrow = Qp + (size_t)(q0 + mh * 16 + l15) * HD_ + quad * 8;
        aQ[mh][0] = *(const bf16x8*)(qrow);
        aQ[mh][1] = *(const bf16x8*)(qrow + 32);
    }

    floatx4 of[2][4];
#pragma unroll
    for (int mh = 0; mh < 2; mh++)
#pragma unroll
        for (int t = 0; t < 4; t++) of[mh][t] = fzero4();
    floatx4 lacc[2];
    lacc[0] = fzero4(); lacc[1] = fzero4();

    const short onebf = (short)0x3F80;   // bf16 1.0
    bf16x8 ones = {onebf, onebf, onebf, onebf, onebf, onebf, onebf, onebf};

    __shared__ unsigned short Kt[64][64];      // 8 KB, XOR-swizzled, single-buffered
    __shared__ unsigned short Vs[64][64];      // 8 KB
    __shared__ unsigned short Pl[4][32][72];   // 18 KB, wave-private, padded

    int srow = lane >> 3;                 // 0..7
    int scol = ((lane & 7) ^ srow) * 8;   // shorts

    int swz0 = (quad ^ (l15 & 7)) * 8;
    int swz1 = ((quad + 4) ^ (l15 & 7)) * 8;

    unsigned short* myP = &Pl[w][0][0];
    for (int kv = kv0; kv < kv0 + 1024; kv += 64) {
#pragma unroll
        for (int i = 0; i < 2; i++) {
            int r0 = 16 * w + 8 * i;
            async16(Kg + (size_t)(kv + r0 + srow) * HD_ + scol, &Kt[r0][0]);
            async16(Vg + (size_t)(r0 + srow) * N_ + kv + scol, &Vs[r0][0]);
        }
        __syncthreads();
        bf16x8 kf[8];
#pragma unroll
        for (int h = 0; h < 4; h++) {
            kf[2 * h]     = *(const bf16x8*)(&Kt[16 * h + l15][swz0]);
            kf[2 * h + 1] = *(const bf16x8*)(&Kt[16 * h + l15][swz1]);
        }
#pragma unroll
        for (int mh = 0; mh < 2; mh++) {
            floatx4 c[4];
#pragma unroll
            for (int h = 0; h < 4; h++) {
                floatx4 cc = fzero4();
                cc = mfma16(aQ[mh][0], kf[2 * h], cc);
                cc = mfma16(aQ[mh][1], kf[2 * h + 1], cc);
                c[h] = cc;
            }
            unsigned short* pw = myP + (mh * 16 + quad * 4) * 72 + l15;
#pragma unroll
            for (int h = 0; h < 4; h++)
#pragma unroll
                for (int r = 0; r < 4; r++)
                    pw[r * 72 + h * 16] = f32_to_bf16(exp2f(c[h][r]));
        }
        bf16x8 vf[8];
#pragma unroll
        for (int t = 0; t < 4; t++) {
            vf[2 * t]     = *(const bf16x8*)(&Vs[16 * t + l15][swz0]);
            vf[2 * t + 1] = *(const bf16x8*)(&Vs[16 * t + l15][swz1]);
        }
#pragma unroll
        for (int mh = 0; mh < 2; mh++) {
            const unsigned short* pr = myP + (mh * 16 + l15) * 72;
            bf16x8 aP0 = *(const bf16x8*)(pr + quad * 8);
            bf16x8 aP1 = *(const bf16x8*)(pr + 32 + quad * 8);
#pragma unroll
            for (int t = 0; t < 4; t++) {
                of[mh][t] = mfma16(aP0, vf[2 * t], of[mh][t]);
                of[mh][t] = mfma16(aP1, vf[2 * t + 1], of[mh][t]);
            }
            lacc[mh] = mfma16(aP0, ones, lacc[mh]);
            lacc[mh] = mfma16(aP1, ones, lacc[mh]);
        }
        __syncthreads();
    }

    unsigned short* Od = Opart + (size_t)split * B_ * N_ * DIM_;
#pragma unroll
    for (int mh = 0; mh < 2; mh++) {
        float inv[4];
#pragma unroll
        for (int r = 0; r < 4; r++) inv[r] = 1.f / lacc[mh][r];
#pragma unroll
        for (int t = 0; t < 4; t++) {
#pragma unroll
            for (int r = 0; r < 4; r++) {
                int t_tok = q0 + mh * 16 + quad * 4 + r;
                int d = 16 * t + l15;
                Od[((size_t)b * N_ + t_tok) * DIM_ + head * HD_ + d] =
                    f32_to_bf16(of[mh][t][r] * inv[r]);
            }
        }
        if (l15 == 0) {
#pragma unroll
            for (int r = 0; r < 4; r++) {
                int t_tok = q0 + mh * 16 + quad * 4 + r;
                lpart[(size_t)split * B_ * NH_ * N_ + (size_t)bh * N_ + t_tok] =
                    lacc[mh][r];
            }
        }
    }
}

extern "C" void kernel_launch(void* const* d_in, const int* in_sizes, int n_in,
                              void* d_out, int out_size, void* d_ws, size_t ws_size,
                              hipStream_t stream) {
    const float* x     = (const float*)d_in[0];
    const float* ln_w  = (const float*)d_in[1];
    const float* ln_b  = (const float*)d_in[2];
    const float* qkv_w = (const float*)d_in[3];
    const float* qkv_b = (const float*)d_in[4];
    const float* out_w = (const float*)d_in[5];
    const float* out_b = (const float*)d_in[6];
    float* out = (float*)d_out;

    char* ws = (char*)d_ws;
    const size_t TOK = (size_t)B_ * N_;                 // 8192
    unsigned short* xn    = (unsigned short*)ws;  ws += TOK * DIM_ * 2;
    unsigned short* wq_bf = (unsigned short*)ws;  ws += (size_t)3 * DIM_ * DIM_ * 2;
    unsigned short* wo_bf = (unsigned short*)ws;  ws += (size_t)DIM_ * DIM_ * 2;
    unsigned short* Qh    = (unsigned short*)ws;  ws += TOK * DIM_ * 2;
    unsigned short* Kh    = (unsigned short*)ws;  ws += TOK * DIM_ * 2;
    unsigned short* Vt    = (unsigned short*)ws;  ws += TOK * DIM_ * 2;
    unsigned short* Opart = (unsigned short*)ws;  ws += (size_t)2 * TOK * DIM_ * 2;
    float*          lpart = (float*)ws;           ws += (size_t)2 * B_ * NH_ * N_ * 4;

    const int NW = 3 * DIM_ * DIM_;
    const int NO = DIM_ * DIM_;

    ln_kernel<<<TOK / 4, 256, 0, stream>>>(x, ln_w, ln_b, xn);
    cvt_kernel<<<(NW + NO + 255) / 256, 256, 0, stream>>>(qkv_w, NW, out_w, NO, wq_bf, wo_bf);
    qkv_gemm<<<dim3(TOK / 128, (3 * DIM_) / 128), 512, 0, stream>>>(xn, wq_bf, qkv_b, Qh, Kh, Vt);
    attn_kernel<<<dim3(N_ / 128, B_ * NH_, 2), 256, 0, stream>>>(Qh, Kh, Vt, Opart, lpart);
    out_gemm_fused<<<dim3(TOK / 64, DIM_ / 128), 256, 0, stream>>>(Opart, lpart, wo_bf, out_b, out);
}